// Round 11
// baseline (4212.487 us; speedup 1.0000x reference)
//
// v11: r10 verbatim base + LSB-tagged fast-path consume (single fabric
// round-trip) with r3 flag-poll fallback; launch safety net retained.
#include <hip/hip_runtime.h>
#include <hip/hip_fp16.h>

#define T_LEN 512
#define DDIM 512
#define HDIM 512
#define BATCH 64
#define NWG_DIR 32      // workgroups per direction
#define UNITS_PER_WG 16 // hidden units per wg -> 64 gate rows (interleaved [unit][gate])

typedef _Float16 v8h __attribute__((ext_vector_type(8)));
typedef float v4f __attribute__((ext_vector_type(4)));
typedef unsigned int v4u __attribute__((ext_vector_type(4)));
typedef unsigned long long u64;

__device__ __forceinline__ float sigf(float x) { return 1.0f / (1.0f + __expf(-x)); }
__device__ __forceinline__ float tanh_fast(float x) { return 2.0f / (1.0f + __expf(-2.0f * x)) - 1.0f; }

// ws layout (identical to r3/r10):
//   [0 .. 1K)        : flags, u32 [dir(2)][wave(4)][sub(32)] packed 4B stride
//   [16K .. 16K+256K): h double buffers: f16 [dir(2)][phase(2)][BATCH][HDIM]
//   [272K ...)       : bw-direction output buffer (f32) when ws permits
// h storage permutation: stored half position p = sub*16 + q*4 + k holds
// true unit sub*16 + k*4 + q; one 8B u64 atomic store per lane => each
// aligned u64 is exactly one producer store (single-copy atomic, no tear).
// TAG: all 4 f16 LSBs of a published u64 = g(t_pub) = ((t_pub+1)>>1)&1.
// Happens-before induction: when a WG is at step t, all WGs completed step
// t-2, so phase t&1 holds only gen t or gen t-2 — which have OPPOSITE tags.
// Zero-init (LSB 0) is the valid tag for t=0. On tag miss: r3 flag fallback.
#define WS_HB_OFF 16384
#define WS_BWOUT_OFF (WS_HB_OFF + 2 * 2 * BATCH * HDIM * 2)
#define OUT_BYTES ((size_t)T_LEN * BATCH * HDIM * 4)
#define WS_NEED_BASE WS_BWOUT_OFF
#define WS_NEED_SPLIT (WS_BWOUT_OFF + OUT_BYTES)
#define LSBM 0x0001000100010001ull

__global__ void __launch_bounds__(256, 1) bilstm_kernel(
    const float* __restrict__ x,
    const float* __restrict__ Wih_fw, const float* __restrict__ Whh_fw,
    const float* __restrict__ Wih_bw, const float* __restrict__ Whh_bw,
    float* __restrict__ out, float* __restrict__ out_bw,
    unsigned char* __restrict__ ws, int split)
{
  const int wg   = blockIdx.x;
  const int dir  = wg >> 5;       // 0 = fw, 1 = bw
  const int sub  = wg & 31;
  const int tid  = threadIdx.x;
  const int w    = tid >> 6;      // wave -> batch block (16 batches)
  const int lane = tid & 63;
  const int n    = lane & 15;     // MFMA col (batch within block) / A-row
  const int q    = lane >> 4;     // MFMA quad
  const int u0   = sub * UNITS_PER_WG;

  // Weights f16, layout [kc(32)][qq(4)][r(64)][8]; r = tile*16 + m, rows
  // interleaved m = ulocal*4 + gate. kc<16: Wih. kc>=16: Whh with columns
  // permuted to stored-h order.
  __shared__ _Float16 Wlds[32 * 4 * 64 * 8];  // 128 KiB

  const float* __restrict__ Wih = dir ? Wih_bw : Wih_fw;
  const float* __restrict__ Whh = dir ? Whh_bw : Whh_fw;

  for (int idx = tid; idx < 65536; idx += 256) {
    const int j    = idx & 7;
    const int r    = (idx >> 3) & 63;
    const int qq   = (idx >> 9) & 3;
    const int kc   = idx >> 11;
    const int tile = r >> 4, m = r & 15;
    const int unit = u0 + tile * 4 + (m >> 2);
    const int gate = m & 3;                      // i,f,g,o
    const int R    = gate * HDIM + unit;
    float wv;
    if (kc < 16) {
      const int k = kc * 32 + qq * 8 + j;
      wv = Wih[(size_t)R * DDIM + k];
    } else {
      const int p = (kc - 16) * 32 + qq * 8 + j;                  // stored pos
      const int U = (p & ~15) | (((p & 3) << 2) | ((p >> 2) & 3)); // true unit
      wv = Whh[(size_t)R * HDIM + U];
    }
    Wlds[idx] = (_Float16)wv;
  }
  __syncthreads();   // one-time: weights ready. NO syncthreads in the loop.

  _Float16* hb = (_Float16*)(ws + WS_HB_OFF) + (size_t)dir * 2 * (BATCH * HDIM);
  unsigned int* flags  = (unsigned int*)ws;
  unsigned int* myflag = flags + (size_t)dir * 128 + (size_t)w * 32 + sub;
  const unsigned int* pollp =
      flags + (size_t)dir * 128 + (size_t)w * 32 + (size_t)(lane & 7) * 4;

  float* myout = dir ? out_bw : out;

  const int b = w * 16 + n;   // batch row this lane owns
  float cA = 0.f, cB = 0.f, cC = 0.f, cD = 0.f;  // units u0+{0,4,8,12}+q

  for (int t = 0; t < T_LEN; ++t) {
    const int tx = dir ? (T_LEN - 1 - t) : t;
    const float*    xrow = x + ((size_t)b * T_LEN + tx) * DDIM;
    const _Float16* hrow = hb + (t & 1) * (BATCH * HDIM) + b * HDIM;

    v4f acc0 = {0.f, 0.f, 0.f, 0.f};  // units u0+q,    gates i,f,g,o
    v4f acc1 = {0.f, 0.f, 0.f, 0.f};  // units u0+4+q
    v4f acc2 = {0.f, 0.f, 0.f, 0.f};  // units u0+8+q
    v4f acc3 = {0.f, 0.f, 0.f, 0.f};  // units u0+12+q

    // ---- x phase: independent of h(t); overlaps producers finishing t-1.
    #pragma unroll
    for (int kc = 0; kc < 16; ++kc) {
      const float4 lo = *(const float4*)(xrow + kc * 32 + q * 8);
      const float4 hi = *(const float4*)(xrow + kc * 32 + q * 8 + 4);
      v8h bf;
      bf[0] = (_Float16)lo.x; bf[1] = (_Float16)lo.y; bf[2] = (_Float16)lo.z; bf[3] = (_Float16)lo.w;
      bf[4] = (_Float16)hi.x; bf[5] = (_Float16)hi.y; bf[6] = (_Float16)hi.z; bf[7] = (_Float16)hi.w;
      const _Float16* wb = &Wlds[(size_t)(kc * 4 + q) * 64 * 8];
      const v8h a0 = *(const v8h*)(wb + (n) * 8);
      const v8h a1 = *(const v8h*)(wb + (16 + n) * 8);
      const v8h a2 = *(const v8h*)(wb + (32 + n) * 8);
      const v8h a3 = *(const v8h*)(wb + (48 + n) * 8);
      acc0 = __builtin_amdgcn_mfma_f32_16x16x32_f16(a0, bf, acc0, 0, 0, 0);
      acc1 = __builtin_amdgcn_mfma_f32_16x16x32_f16(a1, bf, acc1, 0, 0, 0);
      acc2 = __builtin_amdgcn_mfma_f32_16x16x32_f16(a2, bf, acc2, 0, 0, 0);
      acc3 = __builtin_amdgcn_mfma_f32_16x16x32_f16(a3, bf, acc3, 0, 0, 0);
    }

    // ---- consume h(t), FAST PATH: 32 u64 atomic loads (each u64 = one
    // producer store) + LSB tag check. Poll and data = SAME transaction.
    const u64 want = (((unsigned)(t + 1) >> 1) & 1) ? LSBM : 0ull;
    u64 hu[32];
    bool okf = true;
    #pragma unroll
    for (int kc = 0; kc < 16; ++kc) {
      const u64* hp = (const u64*)(hrow + kc * 32 + q * 8);
      hu[2 * kc]     = __hip_atomic_load(hp,     __ATOMIC_RELAXED, __HIP_MEMORY_SCOPE_AGENT);
      hu[2 * kc + 1] = __hip_atomic_load(hp + 1, __ATOMIC_RELAXED, __HIP_MEMORY_SCOPE_AGENT);
    }
    #pragma unroll
    for (int i = 0; i < 32; ++i) okf &= ((hu[i] & LSBM) == want);

    if (!__all(okf)) {
      // ---- FALLBACK (r3/r10 proven): poll flags, then reload fresh.
      {
        const unsigned int tt = (unsigned int)t;
        unsigned int guard = 0;
        for (;;) {
          v4u f;
          asm volatile("global_load_dwordx4 %0, %1, off sc0 sc1\n\t"
                       "s_waitcnt vmcnt(0)"
                       : "=v"(f) : "v"(pollp) : "memory");
          const bool ok = (f[0] >= tt) & (f[1] >= tt) & (f[2] >= tt) & (f[3] >= tt);
          if (__all(ok)) break;
          if (++guard > (1u << 20)) break;  // safety valve — never hit when correct
        }
      }
      __builtin_amdgcn_sched_barrier(0);
      #pragma unroll
      for (int kc = 0; kc < 16; ++kc) {
        const u64* hp = (const u64*)(hrow + kc * 32 + q * 8);
        hu[2 * kc]     = __hip_atomic_load(hp,     __ATOMIC_RELAXED, __HIP_MEMORY_SCOPE_AGENT);
        hu[2 * kc + 1] = __hip_atomic_load(hp + 1, __ATOMIC_RELAXED, __HIP_MEMORY_SCOPE_AGENT);
      }
    }

    // ---- h GEMM (r0-proven u64-pair -> v8h fragment mapping).
    #pragma unroll
    for (int kc = 16; kc < 32; ++kc) {
      union { u64 u[2]; v8h h; } cv;
      cv.u[0] = hu[2 * (kc - 16)];
      cv.u[1] = hu[2 * (kc - 16) + 1];
      const _Float16* wb = &Wlds[(size_t)(kc * 4 + q) * 64 * 8];
      const v8h a0 = *(const v8h*)(wb + (n) * 8);
      const v8h a1 = *(const v8h*)(wb + (16 + n) * 8);
      const v8h a2 = *(const v8h*)(wb + (32 + n) * 8);
      const v8h a3 = *(const v8h*)(wb + (48 + n) * 8);
      acc0 = __builtin_amdgcn_mfma_f32_16x16x32_f16(a0, cv.h, acc0, 0, 0, 0);
      acc1 = __builtin_amdgcn_mfma_f32_16x16x32_f16(a1, cv.h, acc1, 0, 0, 0);
      acc2 = __builtin_amdgcn_mfma_f32_16x16x32_f16(a2, cv.h, acc2, 0, 0, 0);
      acc3 = __builtin_amdgcn_mfma_f32_16x16x32_f16(a3, cv.h, acc3, 0, 0, 0);
    }

    // ---- pointwise LSTM cell.
    cA = sigf(acc0[1]) * cA + sigf(acc0[0]) * tanh_fast(acc0[2]);
    const float hA = sigf(acc0[3]) * tanh_fast(cA);
    cB = sigf(acc1[1]) * cB + sigf(acc1[0]) * tanh_fast(acc1[2]);
    const float hB = sigf(acc1[3]) * tanh_fast(cB);
    cC = sigf(acc2[1]) * cC + sigf(acc2[0]) * tanh_fast(acc2[2]);
    const float hC = sigf(acc2[3]) * tanh_fast(cC);
    cD = sigf(acc3[1]) * cD + sigf(acc3[0]) * tanh_fast(acc3[2]);
    const float hD = sigf(acc3[3]) * tanh_fast(cD);

    // ---- publish h(t+1): one u64 atomic store per lane, all 4 f16 LSBs
    // forced to g(t+1) = ((t+2)>>1)&1; then r3 drain + flag (fallback path).
    {
      union { _Float16 h[4]; u64 u; } pk;
      pk.h[0] = (_Float16)hA;
      pk.h[1] = (_Float16)hB;
      pk.h[2] = (_Float16)hC;
      pk.h[3] = (_Float16)hD;
      u64 pv = pk.u & ~LSBM;
      if (((unsigned)(t + 2) >> 1) & 1) pv |= LSBM;
      u64* hw64 = (u64*)(hb + ((t + 1) & 1) * (BATCH * HDIM));
      __hip_atomic_store(&hw64[b * 128 + sub * 4 + q], pv,
                         __ATOMIC_RELAXED, __HIP_MEMORY_SCOPE_AGENT);
    }
    asm volatile("s_waitcnt vmcnt(0)" ::: "memory");
    if (lane == 0) {
      __hip_atomic_store(myflag, (unsigned int)(t + 1),
                         __ATOMIC_RELAXED, __HIP_MEMORY_SCOPE_AGENT);
    }

    // ---- output: plain L2 stores (split) or device atomics (fallback);
    // drains lazily under the next step's x-phase.
    float* orow = myout + ((size_t)tx * BATCH + b) * HDIM;
    if (split) {
      orow[u0 + q]      = hA;
      orow[u0 + 4 + q]  = hB;
      orow[u0 + 8 + q]  = hC;
      orow[u0 + 12 + q] = hD;
    } else {
      __hip_atomic_fetch_add(orow + u0 + q,      hA, __ATOMIC_RELAXED, __HIP_MEMORY_SCOPE_AGENT);
      __hip_atomic_fetch_add(orow + u0 + 4 + q,  hB, __ATOMIC_RELAXED, __HIP_MEMORY_SCOPE_AGENT);
      __hip_atomic_fetch_add(orow + u0 + 8 + q,  hC, __ATOMIC_RELAXED, __HIP_MEMORY_SCOPE_AGENT);
      __hip_atomic_fetch_add(orow + u0 + 12 + q, hD, __ATOMIC_RELAXED, __HIP_MEMORY_SCOPE_AGENT);
    }
  }
}

__global__ void __launch_bounds__(256) add_kernel(float* __restrict__ out,
                                                  const float* __restrict__ addend) {
  const size_t i = ((size_t)blockIdx.x * 256 + threadIdx.x) * 4;
  float4 a = *(const float4*)(out + i);
  const float4 b = *(const float4*)(addend + i);
  a.x += b.x; a.y += b.y; a.z += b.z; a.w += b.w;
  *(float4*)(out + i) = a;
}

extern "C" void kernel_launch(void* const* d_in, const int* in_sizes, int n_in,
                              void* d_out, int out_size, void* d_ws, size_t ws_size,
                              hipStream_t stream) {
  const float* x      = (const float*)d_in[0];
  const float* Wih_fw = (const float*)d_in[1];
  const float* Whh_fw = (const float*)d_in[2];
  const float* Wih_bw = (const float*)d_in[3];
  const float* Whh_bw = (const float*)d_in[4];
  float* out = (float*)d_out;
  unsigned char* ws = (unsigned char*)d_ws;

  const int split = (ws_size >= (size_t)WS_NEED_SPLIT) ? 1 : 0;
  float* out_bw = split ? (float*)(ws + WS_BWOUT_OFF) : out;

  // flags + h buffers must start at 0 (ws is poisoned 0xAA before each
  // call); zeroed h with LSB 0 is exactly the valid tagged state for t=0.
  hipMemsetAsync(d_ws, 0, (size_t)WS_NEED_BASE, stream);
  if (!split) {
    hipMemsetAsync(d_out, 0, (size_t)out_size * sizeof(float), stream);
  }

  void* args[] = {(void*)&x, (void*)&Wih_fw, (void*)&Whh_fw, (void*)&Wih_bw,
                  (void*)&Whh_bw, (void*)&out, (void*)&out_bw, (void*)&ws,
                  (void*)&split};
  hipError_t err = hipLaunchCooperativeKernel(
      (const void*)bilstm_kernel, dim3(2 * NWG_DIR), dim3(256), args, 0, stream);
  if (err != hipSuccess) {
    // Safety net: co-residency is guaranteed by occupancy (128KB LDS ->
    // 1 WG/CU; 128 WGs < 256 CUs), so a plain launch is equivalent.
    bilstm_kernel<<<dim3(2 * NWG_DIR), dim3(256), 0, stream>>>(
        x, Wih_fw, Whh_fw, Wih_bw, Whh_bw, out, out_bw, ws, split);
  }

  if (split) {
    const int n4 = (int)(OUT_BYTES / 16);
    add_kernel<<<dim3(n4 / 256), dim3(256), 0, stream>>>(out, out_bw);
  }
}